// Round 5
// baseline (226.136 us; speedup 1.0000x reference)
//
#include <hip/hip_runtime.h>

#define NUM_JOINTS 24

typedef float fvec4 __attribute__((ext_vector_type(4)));

// Ancestor path (root -> joint) for each joint, padded with -1.
__device__ __constant__ int d_chain[NUM_JOINTS][9] = {
    {0,-1,-1,-1,-1,-1,-1,-1,-1},
    {0,1,-1,-1,-1,-1,-1,-1,-1},
    {0,2,-1,-1,-1,-1,-1,-1,-1},
    {0,3,-1,-1,-1,-1,-1,-1,-1},
    {0,1,4,-1,-1,-1,-1,-1,-1},
    {0,2,5,-1,-1,-1,-1,-1,-1},
    {0,3,6,-1,-1,-1,-1,-1,-1},
    {0,1,4,7,-1,-1,-1,-1,-1},
    {0,2,5,8,-1,-1,-1,-1,-1},
    {0,3,6,9,-1,-1,-1,-1,-1},
    {0,1,4,7,10,-1,-1,-1,-1},
    {0,2,5,8,11,-1,-1,-1,-1},
    {0,3,6,9,12,-1,-1,-1,-1},
    {0,3,6,9,13,-1,-1,-1,-1},
    {0,3,6,9,14,-1,-1,-1,-1},
    {0,3,6,9,12,15,-1,-1,-1},
    {0,3,6,9,13,16,-1,-1,-1},
    {0,3,6,9,14,17,-1,-1,-1},
    {0,3,6,9,13,16,18,-1,-1},
    {0,3,6,9,14,17,19,-1,-1},
    {0,3,6,9,13,16,18,20,-1},
    {0,3,6,9,14,17,19,21,-1},
    {0,3,6,9,13,16,18,20,22},
    {0,3,6,9,14,17,19,21,23},
};

// a*s + c  (vector * scalar + vector)
__device__ __forceinline__ fvec4 fma4s(fvec4 a, float s, fvec4 c) {
    fvec4 r;
    r.x = fmaf(a.x, s, c.x); r.y = fmaf(a.y, s, c.y);
    r.z = fmaf(a.z, s, c.z); r.w = fmaf(a.w, s, c.w);
    return r;
}
// a*b + c  (elementwise)
__device__ __forceinline__ fvec4 fma4v(fvec4 a, fvec4 b, fvec4 c) {
    fvec4 r;
    r.x = fmaf(a.x, b.x, c.x); r.y = fmaf(a.y, b.y, c.y);
    r.z = fmaf(a.z, b.z, c.z); r.w = fmaf(a.w, b.w, c.w);
    return r;
}
// a*s (vector * scalar)
__device__ __forceinline__ fvec4 mul4s(fvec4 a, float s) {
    fvec4 r; r.x = a.x * s; r.y = a.y * s; r.z = a.z * s; r.w = a.w * s;
    return r;
}

// R12 model (fits R0/R7/R10/R11): per-CU read rate saturates at ~12.3 GB/s
// (= m13 copy read rate) and needs ~8 FULL waves/CU; all residual loss is
// per-CU work quantization. R0: loaded CUs at ceiling, 31% imbalance loss.
// R10: balanced work but 196/256 active threads -> rate fell proportionally.
// This version: balanced work AND full waves -- 512 blocks (exactly 2/CU),
// 256 threads all active, task = one fvec4 chunk, 3-4 chunks/thread via
// block-stride loop (quantization +-0.06% at block level). Consecutive
// threads -> consecutive chunks (R11 locality kept). nt loads+stores kept
// (R9: removing nt loads costs +15us). unroll-4 k-loop: ~4KB/wave in
// flight (between R10-starvation and R8-flood).
// Predicted: kernel ~71 -> ~56us, dur 222.7 -> ~208-214.
__global__ __launch_bounds__(256) void skin_bal4_kernel(
    const float* __restrict__ normals,
    const float* __restrict__ pose,
    const float* __restrict__ weights,
    float* __restrict__ out,
    int N) {
    __shared__ float L[NUM_JOINTS][9];
    __shared__ fvec4 Rl[NUM_JOINTS][3];  // global rots, rows padded 9->12 floats

    const int b = blockIdx.y;
    const int tid = threadIdx.x;

    // --- chain computation (lanes 0..23 of wave 0) ---
    if (tid < NUM_JOINTS) {
        float x = pose[b * 72 + tid * 3 + 0];
        float y = pose[b * 72 + tid * 3 + 1];
        float z = pose[b * 72 + tid * 3 + 2];
        // reference: angle = norm(axisang + 1e-8); axis = axisang / angle
        float ax = x + 1e-8f, ay = y + 1e-8f, az = z + 1e-8f;
        float angle = sqrtf(ax * ax + ay * ay + az * az);
        float inv = 1.0f / angle;
        float ux = x * inv, uy = y * inv, uz = z * inv;
        float c = __cosf(angle), s = __sinf(angle), t = 1.0f - c;
        L[tid][0] = c + t * ux * ux;
        L[tid][1] = t * ux * uy - s * uz;
        L[tid][2] = t * ux * uz + s * uy;
        L[tid][3] = t * uy * ux + s * uz;
        L[tid][4] = c + t * uy * uy;
        L[tid][5] = t * uy * uz - s * ux;
        L[tid][6] = t * uz * ux - s * uy;
        L[tid][7] = t * uz * uy + s * ux;
        L[tid][8] = c + t * uz * uz;
    }
    __syncthreads();

    if (tid < NUM_JOINTS) {
        // each lane composes its own ancestor path: G = L[c0] @ L[c1] @ ...
        float G[9];
        int j0 = d_chain[tid][0];  // always 0
        #pragma unroll
        for (int e = 0; e < 9; e++) G[e] = L[j0][e];
        #pragma unroll
        for (int d = 1; d < 9; d++) {
            int j = d_chain[tid][d];
            if (j >= 0) {
                float T[9];
                #pragma unroll
                for (int r = 0; r < 3; r++) {
                    #pragma unroll
                    for (int cc = 0; cc < 3; cc++) {
                        T[r * 3 + cc] = G[r * 3 + 0] * L[j][0 * 3 + cc]
                                      + G[r * 3 + 1] * L[j][1 * 3 + cc]
                                      + G[r * 3 + 2] * L[j][2 * 3 + cc];
                    }
                }
                #pragma unroll
                for (int e = 0; e < 9; e++) G[e] = T[e];
            }
        }
        float* Rf = (float*)Rl;
        #pragma unroll
        for (int e = 0; e < 9; e++) Rf[tid * 12 + e] = G[e];
    }
    __syncthreads();

    // --- skinning: balanced contiguous slice of fvec4 chunks per block ---
    const int nf4 = N >> 2;                       // float4s per row
    const int gx = gridDim.x;
    const int per = nf4 / gx;                     // 781 for N=100000, gx=32
    const int rem = nf4 - per * gx;               // 8
    const int bx = blockIdx.x;
    const int base = bx * per + (bx < rem ? bx : rem);
    const int cnt = per + (bx < rem ? 1 : 0);

    const fvec4* __restrict__ Wb = (const fvec4*)(weights + (size_t)b * NUM_JOINTS * N);
    const fvec4* __restrict__ Nb = (const fvec4*)(normals + (size_t)b * 3 * N);
    fvec4* __restrict__ Ob = (fvec4*)(out + (size_t)b * 3 * N);

    // all 256 threads active; 3-4 iterations each; consecutive threads hit
    // consecutive chunks (coalesced 64x16B, block covers contiguous 4KB+).
    for (int i = tid; i < cnt; i += 256) {
        const int c = base + i;

        fvec4 nx = __builtin_nontemporal_load(&Nb[(size_t)0 * nf4 + c]);
        fvec4 ny = __builtin_nontemporal_load(&Nb[(size_t)1 * nf4 + c]);
        fvec4 nz = __builtin_nontemporal_load(&Nb[(size_t)2 * nf4 + c]);
        fvec4 o0 = (fvec4)(0.f), o1 = (fvec4)(0.f), o2 = (fvec4)(0.f);

        #pragma unroll 4
        for (int k = 0; k < NUM_JOINTS; k++) {
            fvec4 w = __builtin_nontemporal_load(&Wb[(size_t)k * nf4 + c]);
            fvec4 r0 = Rl[k][0];  // {M00,M01,M02,M10}
            fvec4 r1 = Rl[k][1];  // {M11,M12,M20,M21}
            fvec4 r2 = Rl[k][2];  // {M22,pad,pad,pad}
            fvec4 t0 = fma4s(nx, r0.x, fma4s(ny, r0.y, mul4s(nz, r0.z)));
            fvec4 t1 = fma4s(nx, r0.w, fma4s(ny, r1.x, mul4s(nz, r1.y)));
            fvec4 t2 = fma4s(nx, r1.z, fma4s(ny, r1.w, mul4s(nz, r2.x)));
            o0 = fma4v(w, t0, o0);
            o1 = fma4v(w, t1, o1);
            o2 = fma4v(w, t2, o2);
        }

        __builtin_nontemporal_store(o0, &Ob[(size_t)0 * nf4 + c]);
        __builtin_nontemporal_store(o1, &Ob[(size_t)1 * nf4 + c]);
        __builtin_nontemporal_store(o2, &Ob[(size_t)2 * nf4 + c]);
    }

    // generic tail: vertices [4*nf4, N) (empty for N=100000: 4 | 100000)
    if (blockIdx.x == 0 && tid == 0) {
        const float* Rf = (const float*)Rl;
        for (int n = nf4 * 4; n < N; n++) {
            float vx = normals[(size_t)b * 3 * N + 0 * N + n];
            float vy = normals[(size_t)b * 3 * N + 1 * N + n];
            float vz = normals[(size_t)b * 3 * N + 2 * N + n];
            float s0 = 0.f, s1 = 0.f, s2 = 0.f;
            for (int k = 0; k < NUM_JOINTS; k++) {
                float w = weights[(size_t)b * NUM_JOINTS * N + (size_t)k * N + n];
                float t0 = Rf[k*12+0] * vx + Rf[k*12+1] * vy + Rf[k*12+2] * vz;
                float t1 = Rf[k*12+3] * vx + Rf[k*12+4] * vy + Rf[k*12+5] * vz;
                float t2 = Rf[k*12+6] * vx + Rf[k*12+7] * vy + Rf[k*12+8] * vz;
                s0 = fmaf(w, t0, s0); s1 = fmaf(w, t1, s1); s2 = fmaf(w, t2, s2);
            }
            out[(size_t)b * 3 * N + 0 * N + n] = s0;
            out[(size_t)b * 3 * N + 1 * N + n] = s1;
            out[(size_t)b * 3 * N + 2 * N + n] = s2;
        }
    }
}

extern "C" void kernel_launch(void* const* d_in, const int* in_sizes, int n_in,
                              void* d_out, int out_size, void* d_ws, size_t ws_size,
                              hipStream_t stream) {
    const float* normals = (const float*)d_in[0];  // (B,3,N)
    const float* pose = (const float*)d_in[1];     // (B,72)
    const float* weights = (const float*)d_in[2];  // (B,24,N)
    float* out = (float*)d_out;                    // (B,3,N)

    const int B = in_sizes[1] / 72;
    const int N = in_sizes[0] / (3 * B);

    // 512 blocks total = exactly 2 per CU on 256 CUs, all threads active.
    int gx = 512 / B;
    if (gx < 1) gx = 1;
    skin_bal4_kernel<<<dim3(gx, B), dim3(256), 0, stream>>>(normals, pose, weights, out, N);
}

// Round 6
// 221.874 us; speedup vs baseline: 1.0192x; 1.0192x over previous
//
#include <hip/hip_runtime.h>

#define NUM_JOINTS 24

typedef float fvec4 __attribute__((ext_vector_type(4)));

// Ancestor path (root -> joint) for each joint, padded with -1.
__device__ __constant__ int d_chain[NUM_JOINTS][9] = {
    {0,-1,-1,-1,-1,-1,-1,-1,-1},
    {0,1,-1,-1,-1,-1,-1,-1,-1},
    {0,2,-1,-1,-1,-1,-1,-1,-1},
    {0,3,-1,-1,-1,-1,-1,-1,-1},
    {0,1,4,-1,-1,-1,-1,-1,-1},
    {0,2,5,-1,-1,-1,-1,-1,-1},
    {0,3,6,-1,-1,-1,-1,-1,-1},
    {0,1,4,7,-1,-1,-1,-1,-1},
    {0,2,5,8,-1,-1,-1,-1,-1},
    {0,3,6,9,-1,-1,-1,-1,-1},
    {0,1,4,7,10,-1,-1,-1,-1},
    {0,2,5,8,11,-1,-1,-1,-1},
    {0,3,6,9,12,-1,-1,-1,-1},
    {0,3,6,9,13,-1,-1,-1,-1},
    {0,3,6,9,14,-1,-1,-1,-1},
    {0,3,6,9,12,15,-1,-1,-1},
    {0,3,6,9,13,16,-1,-1,-1},
    {0,3,6,9,14,17,-1,-1,-1},
    {0,3,6,9,13,16,18,-1,-1},
    {0,3,6,9,14,17,19,-1,-1},
    {0,3,6,9,13,16,18,20,-1},
    {0,3,6,9,14,17,19,21,-1},
    {0,3,6,9,13,16,18,20,22},
    {0,3,6,9,14,17,19,21,23},
};

// a*s + c  (vector * scalar + vector)
__device__ __forceinline__ fvec4 fma4s(fvec4 a, float s, fvec4 c) {
    fvec4 r;
    r.x = fmaf(a.x, s, c.x); r.y = fmaf(a.y, s, c.y);
    r.z = fmaf(a.z, s, c.z); r.w = fmaf(a.w, s, c.w);
    return r;
}
// a*b + c  (elementwise)
__device__ __forceinline__ fvec4 fma4v(fvec4 a, fvec4 b, fvec4 c) {
    fvec4 r;
    r.x = fmaf(a.x, b.x, c.x); r.y = fmaf(a.y, b.y, c.y);
    r.z = fmaf(a.z, b.z, c.z); r.w = fmaf(a.w, b.w, c.w);
    return r;
}
// a*s (vector * scalar)
__device__ __forceinline__ fvec4 mul4s(fvec4 a, float s) {
    fvec4 r; r.x = a.x * s; r.y = a.y * s; r.z = a.z * s; r.w = a.w * s;
    return r;
}

// R13 = exact replication of R11 (best measured: 222.7us).
// Ledger: R8 depth +25, R9 no-nt-loads +15, R10 partial-wave balance +8.4,
// R11 wave-blocked locality -2.2 (best), R12 fine-task balance +3.4.
// Model: aggregate service-rate plateau (~2.7 TB/s combined for this
// 27-stream 9:1 read:write pattern), insensitive to all source-level
// geometry; concurrency not binding (>=32KB/CU in flight vs ~11KB needed).
// This resubmission restores the best kernel and replicates 222.7 vs
// 226.1 (noise check). Pre-commit: land 221-227 -> declare ROOFLINE next.
__global__ __launch_bounds__(256) void skin_fused16_kernel(
    const float* __restrict__ normals,
    const float* __restrict__ pose,
    const float* __restrict__ weights,
    float* __restrict__ out,
    int N) {
    __shared__ float L[NUM_JOINTS][9];
    __shared__ fvec4 Rl[NUM_JOINTS][3];  // global rots, rows padded 9->12 floats

    const int b = blockIdx.y;
    const int tid = threadIdx.x;

    // --- chain computation (lanes 0..23 of wave 0) ---
    if (tid < NUM_JOINTS) {
        float x = pose[b * 72 + tid * 3 + 0];
        float y = pose[b * 72 + tid * 3 + 1];
        float z = pose[b * 72 + tid * 3 + 2];
        // reference: angle = norm(axisang + 1e-8); axis = axisang / angle
        float ax = x + 1e-8f, ay = y + 1e-8f, az = z + 1e-8f;
        float angle = sqrtf(ax * ax + ay * ay + az * az);
        float inv = 1.0f / angle;
        float ux = x * inv, uy = y * inv, uz = z * inv;
        float c = __cosf(angle), s = __sinf(angle), t = 1.0f - c;
        L[tid][0] = c + t * ux * ux;
        L[tid][1] = t * ux * uy - s * uz;
        L[tid][2] = t * ux * uz + s * uy;
        L[tid][3] = t * uy * ux + s * uz;
        L[tid][4] = c + t * uy * uy;
        L[tid][5] = t * uy * uz - s * ux;
        L[tid][6] = t * uz * ux - s * uy;
        L[tid][7] = t * uz * uy + s * ux;
        L[tid][8] = c + t * uz * uz;
    }
    __syncthreads();

    if (tid < NUM_JOINTS) {
        // each lane composes its own ancestor path: G = L[c0] @ L[c1] @ ...
        float G[9];
        int j0 = d_chain[tid][0];  // always 0
        #pragma unroll
        for (int e = 0; e < 9; e++) G[e] = L[j0][e];
        #pragma unroll
        for (int d = 1; d < 9; d++) {
            int j = d_chain[tid][d];
            if (j >= 0) {
                float T[9];
                #pragma unroll
                for (int r = 0; r < 3; r++) {
                    #pragma unroll
                    for (int cc = 0; cc < 3; cc++) {
                        T[r * 3 + cc] = G[r * 3 + 0] * L[j][0 * 3 + cc]
                                      + G[r * 3 + 1] * L[j][1 * 3 + cc]
                                      + G[r * 3 + 2] * L[j][2 * 3 + cc];
                    }
                }
                #pragma unroll
                for (int e = 0; e < 9; e++) G[e] = T[e];
            }
        }
        float* Rf = (float*)Rl;
        #pragma unroll
        for (int e = 0; e < 9; e++) Rf[tid * 12 + e] = G[e];
    }
    __syncthreads();

    // --- skinning ---
    const int q = blockIdx.x * blockDim.x + tid;
    const int nf4 = N >> 2;                       // float4s per row

    const fvec4* __restrict__ Wb = (const fvec4*)(weights + (size_t)b * NUM_JOINTS * N);
    const fvec4* __restrict__ Nb = (const fvec4*)(normals + (size_t)b * 3 * N);
    fvec4* __restrict__ Ob = (fvec4*)(out + (size_t)b * 3 * N);

    if (nf4 > 0) {
        // wave-blocked group mapping: wave-group wg covers chunks
        // [wg*256, wg*256+256); lane l takes g*64 + l within it.
        const int wg = q >> 6;
        const int lane = q & 63;
        int cg[4];
        bool ok[4];
        bool any = false;
        #pragma unroll
        for (int g = 0; g < 4; g++) {
            int c = wg * 256 + g * 64 + lane;
            ok[g] = (c < nf4);
            any = any || ok[g];
            cg[g] = ok[g] ? c : (nf4 - 1);  // clamp: safe load, store masked
        }

        if (any) {
            fvec4 nx[4], ny[4], nz[4], o0[4], o1[4], o2[4];
            #pragma unroll
            for (int g = 0; g < 4; g++) {
                nx[g] = __builtin_nontemporal_load(&Nb[(size_t)0 * nf4 + cg[g]]);
                ny[g] = __builtin_nontemporal_load(&Nb[(size_t)1 * nf4 + cg[g]]);
                nz[g] = __builtin_nontemporal_load(&Nb[(size_t)2 * nf4 + cg[g]]);
                o0[g] = (fvec4)(0.f); o1[g] = (fvec4)(0.f); o2[g] = (fvec4)(0.f);
            }

            #pragma unroll 2
            for (int k = 0; k < NUM_JOINTS; k++) {
                fvec4 w[4];
                #pragma unroll
                for (int g = 0; g < 4; g++)
                    w[g] = __builtin_nontemporal_load(&Wb[(size_t)k * nf4 + cg[g]]);
                fvec4 r0 = Rl[k][0];  // {M00,M01,M02,M10}
                fvec4 r1 = Rl[k][1];  // {M11,M12,M20,M21}
                fvec4 r2 = Rl[k][2];  // {M22,pad,pad,pad}
                #pragma unroll
                for (int g = 0; g < 4; g++) {
                    fvec4 t0 = fma4s(nx[g], r0.x, fma4s(ny[g], r0.y, mul4s(nz[g], r0.z)));
                    fvec4 t1 = fma4s(nx[g], r0.w, fma4s(ny[g], r1.x, mul4s(nz[g], r1.y)));
                    fvec4 t2 = fma4s(nx[g], r1.z, fma4s(ny[g], r1.w, mul4s(nz[g], r2.x)));
                    o0[g] = fma4v(w[g], t0, o0[g]);
                    o1[g] = fma4v(w[g], t1, o1[g]);
                    o2[g] = fma4v(w[g], t2, o2[g]);
                }
            }

            #pragma unroll
            for (int g = 0; g < 4; g++) {
                if (ok[g]) {
                    __builtin_nontemporal_store(o0[g], &Ob[(size_t)0 * nf4 + cg[g]]);
                    __builtin_nontemporal_store(o1[g], &Ob[(size_t)1 * nf4 + cg[g]]);
                    __builtin_nontemporal_store(o2[g], &Ob[(size_t)2 * nf4 + cg[g]]);
                }
            }
        }
    }

    // generic tail: vertices [4*nf4, N) (empty for N=100000: 4 | 100000)
    if (blockIdx.x == 0 && tid == 0) {
        const float* Rf = (const float*)Rl;
        for (int n = nf4 * 4; n < N; n++) {
            float vx = normals[(size_t)b * 3 * N + 0 * N + n];
            float vy = normals[(size_t)b * 3 * N + 1 * N + n];
            float vz = normals[(size_t)b * 3 * N + 2 * N + n];
            float s0 = 0.f, s1 = 0.f, s2 = 0.f;
            for (int k = 0; k < NUM_JOINTS; k++) {
                float w = weights[(size_t)b * NUM_JOINTS * N + (size_t)k * N + n];
                float t0 = Rf[k*12+0] * vx + Rf[k*12+1] * vy + Rf[k*12+2] * vz;
                float t1 = Rf[k*12+3] * vx + Rf[k*12+4] * vy + Rf[k*12+5] * vz;
                float t2 = Rf[k*12+6] * vx + Rf[k*12+7] * vy + Rf[k*12+8] * vz;
                s0 = fmaf(w, t0, s0); s1 = fmaf(w, t1, s1); s2 = fmaf(w, t2, s2);
            }
            out[(size_t)b * 3 * N + 0 * N + n] = s0;
            out[(size_t)b * 3 * N + 1 * N + n] = s1;
            out[(size_t)b * 3 * N + 2 * N + n] = s2;
        }
    }
}

extern "C" void kernel_launch(void* const* d_in, const int* in_sizes, int n_in,
                              void* d_out, int out_size, void* d_ws, size_t ws_size,
                              hipStream_t stream) {
    const float* normals = (const float*)d_in[0];  // (B,3,N)
    const float* pose = (const float*)d_in[1];     // (B,72)
    const float* weights = (const float*)d_in[2];  // (B,24,N)
    float* out = (float*)d_out;                    // (B,3,N)

    const int B = in_sizes[1] / 72;
    const int N = in_sizes[0] / (3 * B);

    // one thread per 16 verts, wave-blocked: wave-group wg covers 256
    // consecutive chunks; q spans ngroups*64 threads. (round-0 geometry:
    // 25 blocks/batch x 16 batches = 400 blocks for N=100000)
    const int nf4 = N >> 2;
    const int ngroups = (nf4 + 255) / 256;
    const int qspan = ngroups * 64;
    const int gx = (qspan + 255) / 256 > 0 ? (qspan + 255) / 256 : 1;
    skin_fused16_kernel<<<dim3(gx, B), dim3(256), 0, stream>>>(normals, pose, weights, out, N);
}